// Round 2
// baseline (443.054 us; speedup 1.0000x reference)
//
#include <hip/hip_runtime.h>

// BSplineLayer: piecewise-linear spline eval.
// u: [4096,64,256] f32 (channel = fastest axis), knots/coefs: [256,64] f32.
// out[e] = c0 + (x-k0)/(k1-k0+eps) * (c1-c0), segment from searchsorted(left).
//
// v2 changes (latency-hiding round):
//  - Channel group 64 -> 32 (8 groups): LDS/block 33.3KB -> 16.6KB, so
//    residency goes 4 -> 8 blocks/CU = 32 waves/CU (100% occupancy).
//    __launch_bounds__(256,8) pins VGPR <= 64 to guarantee it.
//  - Depth-1 software prefetch: next tile's float4 load is issued before
//    computing the current tile -> 2 loads in flight per wave; HBM latency
//    hides under the previous iteration's LDS reads + VALU.
//  - Nontemporal load/store on the streamed u/out (read-once/write-once;
//    keeps the 64KB knots/coefs resident in L2 for per-block staging).
//    NOTE: __builtin_nontemporal_* requires a NATIVE vector type, not HIP's
//    float4 class -> use ext_vector_type(4).
//
// Carried over:
//  - knots+coefs staged in LDS with stride 65 (bank = (c+j)%32, j random
//    across lanes -> ~2-way avg conflict = free).
//  - float4 I/O: lanes 0..7 cover 8 float4 columns = 128B contiguous
//    segments per row -> fully coalesced.
//  - Analytic segment guess + exact-compare fixup loops (exact for uniform
//    knots, correct for any sorted knots, ~0 fixup iterations here).

#define EPS 1e-6f
#define NCH_GROUP 32
#define STRIDE 65          // +1 pad: bank = (c + j) % 32
#define NGROUPS 8
#define BLOCKS_PER_GROUP 256
#define ROWS_PER_TILE 32   // 256 threads / 8 col4-slots

typedef float f32x4 __attribute__((ext_vector_type(4)));

__global__ __launch_bounds__(256, 8) void bspline_kernel(
    const float* __restrict__ u, const float* __restrict__ knots,
    const float* __restrict__ coefs, float* __restrict__ out, int n_rows)
{
    __shared__ float sK[NCH_GROUP * STRIDE];
    __shared__ float sC[NCH_GROUP * STRIDE];

    const int t = threadIdx.x;
    const int g = blockIdx.x & (NGROUPS - 1);   // channel group 0..7
    const int b = blockIdx.x >> 3;              // block index within group

    // Stage this group's knots & coefs (2048 floats each, L2-resident after
    // the first blocks) into padded LDS.
    const float* gk = knots + (size_t)g * NCH_GROUP * 64;
    const float* gc = coefs + (size_t)g * NCH_GROUP * 64;
    for (int i = t; i < NCH_GROUP * 64; i += 256) {
        int c = i >> 6;
        int k = i & 63;
        sK[c * STRIDE + k] = gk[i];
        sC[c * STRIDE + k] = gc[i];
    }
    __syncthreads();

    const int col4 = t & 7;         // which float4 column within the group
    const int rsub = t >> 3;        // row 0..31 within a tile
    const int lc = col4 * 4;        // local channel base (0..28)

    // Per-channel guess parameters (channels are fixed for this thread).
    float kmin[4], scale[4];
#pragma unroll
    for (int cc = 0; cc < 4; ++cc) {
        float klo = sK[(lc + cc) * STRIDE + 0];
        float khi = sK[(lc + cc) * STRIDE + 63];
        kmin[cc] = klo;
        scale[cc] = 63.0f * __builtin_amdgcn_rcpf(khi - klo);
    }

    const f32x4* u4 = (const f32x4*)u;
    f32x4* o4 = (f32x4*)out;
    const int colbase = g * 8 + col4;           // float4 column in [0,64)
    const int ntiles = n_rows / ROWS_PER_TILE;

    int rt = b;
    if (rt >= ntiles) return;
    size_t idx = (size_t)(rt * ROWS_PER_TILE + rsub) * 64 + colbase;
    f32x4 x4 = __builtin_nontemporal_load(&u4[idx]);

    for (;;) {
        // Issue next tile's load before computing this one (depth-1 pipeline).
        const int rtn = rt + BLOCKS_PER_GROUP;
        const bool more = rtn < ntiles;          // wave-uniform branch
        size_t idxn = idx;
        f32x4 xn = x4;
        if (more) {
            idxn = (size_t)(rtn * ROWS_PER_TILE + rsub) * 64 + colbase;
            xn = __builtin_nontemporal_load(&u4[idxn]);
        }

        f32x4 r;
#pragma unroll
        for (int cc = 0; cc < 4; ++cc) {
            float x = x4[cc];
            const float* kp = &sK[(lc + cc) * STRIDE];
            const float* cp = &sC[(lc + cc) * STRIDE];

            // Predictor: analytic segment guess (exact for uniform knots).
            float xs = (x - kmin[cc]) * scale[cc];
            int j = (int)xs;
            j = max(0, min(62, j));
            float k0 = kp[j];
            float k1 = kp[j + 1];
            // Corrector: exact-compare fixups. Final j satisfies
            // (j==0 || k[j] < x) && (j==62 || k[j+1] >= x)
            //   == clamp(searchsorted_left(k,x)-1, 0, 62) for any sorted k.
            while (j > 0 && k0 >= x) { --j; k1 = k0; k0 = kp[j]; }
            while (j < 62 && k1 < x) { ++j; k0 = k1; k1 = kp[j + 1]; }

            float tt = (x - k0) * __builtin_amdgcn_rcpf(k1 - k0 + EPS);
            float c0 = cp[j];
            float c1 = cp[j + 1];
            r[cc] = fmaf(tt, c1 - c0, c0);
        }
        __builtin_nontemporal_store(r, &o4[idx]);

        if (!more) break;
        rt = rtn; idx = idxn; x4 = xn;
    }
}

extern "C" void kernel_launch(void* const* d_in, const int* in_sizes, int n_in,
                              void* d_out, int out_size, void* d_ws, size_t ws_size,
                              hipStream_t stream) {
    const float* u     = (const float*)d_in[0];
    const float* knots = (const float*)d_in[1];
    const float* coefs = (const float*)d_in[2];
    float* out = (float*)d_out;

    int n_rows = in_sizes[0] / 256;   // 262144 rows of 256 channels

    dim3 grid(NGROUPS * BLOCKS_PER_GROUP);   // 2048 blocks = 8/CU, one wave
    dim3 block(256);
    bspline_kernel<<<grid, block, 0, stream>>>(u, knots, coefs, out, n_rows);
}